// Round 1
// baseline (482.598 us; speedup 1.0000x reference)
//
#include <hip/hip_runtime.h>
#include <hip/hip_bf16.h>
#include <stdint.h>

// Problem dims (fixed by the reference)
constexpr int Mdim = 256;    // batch
constexpr int Ndim = 4096;   // codes E
constexpr int Kdim = 16384;  // EMB = C*D*H*W

// GEMM tiling
constexpr int MT = 128;
constexpr int NT = 128;
constexpr int KS = 16;            // split-K factor -> grid 32*2*16 = 1024 blocks
constexpr int KC = Kdim / KS;     // 1024 K per block
constexpr int BK = 32;            // K per LDS tile (one 16x16x32 MFMA step)
constexpr int NITER = KC / BK;    // 32
constexpr int LDK = 40;           // padded LDS row stride in bf16 elems (2-way bank aliasing = free)

typedef __attribute__((ext_vector_type(8))) short short8;  // 8 x bf16 bits (4 VGPR)
typedef __attribute__((ext_vector_type(4))) float f32x4;   // MFMA accumulator

static_assert(Mdim % MT == 0 && Ndim % NT == 0 && Kdim % (KS * BK) == 0, "tiling");

__device__ __forceinline__ unsigned short f32_to_bf16(float f) {
  union { float f; unsigned int u; } v; v.f = f;
  unsigned int r = v.u + 0x7fffu + ((v.u >> 16) & 1u);  // RNE
  return (unsigned short)(r >> 16);
}
__device__ __forceinline__ float bf16_to_f32(unsigned short h) {
  union { unsigned int u; float f; } v; v.u = ((unsigned int)h) << 16;
  return v.f;
}

// scores[b][n] += sum_kchunk( ||e_n||^2_chunk - 2 * x_b . e_n |_chunk )
// via split-bf16 (hi+lo) 3-MFMA emulation of fp32 matmul.
__global__ __launch_bounds__(256) void k_gemm(const float* __restrict__ x,
                                              const float* __restrict__ e,
                                              float* __restrict__ scores) {
  __shared__ alignas(16) unsigned short lds[4 * 128 * LDK];  // 40 KiB
  __shared__ float esq_part[256];
  __shared__ float esq_sh[128];
  unsigned short* Ahi = lds;
  unsigned short* Alo = lds + 128 * LDK;
  unsigned short* Bhi = lds + 2 * 128 * LDK;
  unsigned short* Blo = lds + 3 * 128 * LDK;

  const int t  = threadIdx.x;
  const int n0 = blockIdx.x * NT;
  const int m0 = blockIdx.y * MT;
  const int k0 = blockIdx.z * KC;

  // staging: 2 threads per row, 16 contiguous floats each
  const int r  = t >> 1;
  const int kq = (t & 1) * 16;
  const float* xp = x + (size_t)(m0 + r) * Kdim + k0 + kq;
  const float* ep = e + (size_t)(n0 + r) * Kdim + k0 + kq;

  // wave -> 64x64 quadrant, 4x4 subtiles of 16x16
  const int wave = t >> 6;
  const int lane = t & 63;
  const int wm   = (wave & 1) * 64;
  const int wn   = (wave >> 1) * 64;
  const int lcol = lane & 15;
  const int quad = lane >> 4;

  f32x4 acc[4][4] = {};
  float esq_acc = 0.0f;

  float4 bufA[4], bufB[4];
#pragma unroll
  for (int g = 0; g < 4; ++g) {  // prefetch iter 0
    bufA[g] = ((const float4*)xp)[g];
    bufB[g] = ((const float4*)ep)[g];
  }

  for (int it = 0; it < NITER; ++it) {
    // ---- convert staged fp32 -> bf16 hi/lo, accumulate ||e||^2 ----
    float fa[16], fb[16];
#pragma unroll
    for (int g = 0; g < 4; ++g) {
      fa[4*g+0] = bufA[g].x; fa[4*g+1] = bufA[g].y; fa[4*g+2] = bufA[g].z; fa[4*g+3] = bufA[g].w;
      fb[4*g+0] = bufB[g].x; fb[4*g+1] = bufB[g].y; fb[4*g+2] = bufB[g].z; fb[4*g+3] = bufB[g].w;
    }
    short8 AH[2], AL[2], BH[2], BL[2];
#pragma unroll
    for (int g = 0; g < 2; ++g) {
#pragma unroll
      for (int j = 0; j < 8; ++j) {
        float va = fa[8*g+j];
        unsigned short ha = f32_to_bf16(va);
        AH[g][j] = (short)ha;
        AL[g][j] = (short)f32_to_bf16(va - bf16_to_f32(ha));
        float vb = fb[8*g+j];
        esq_acc += vb * vb;
        unsigned short hb = f32_to_bf16(vb);
        BH[g][j] = (short)hb;
        BL[g][j] = (short)f32_to_bf16(vb - bf16_to_f32(hb));
      }
    }
    __syncthreads();  // previous iter's fragment reads complete
#pragma unroll
    for (int g = 0; g < 2; ++g) {
      *(short8*)&Ahi[r*LDK + kq + 8*g] = AH[g];
      *(short8*)&Alo[r*LDK + kq + 8*g] = AL[g];
      *(short8*)&Bhi[r*LDK + kq + 8*g] = BH[g];
      *(short8*)&Blo[r*LDK + kq + 8*g] = BL[g];
    }
    __syncthreads();  // tile visible

    // prefetch next iter's globals (vmcnt overlaps the MFMA phase)
    if (it + 1 < NITER) {
      const float* xn = xp + (size_t)(it + 1) * BK;
      const float* en = ep + (size_t)(it + 1) * BK;
#pragma unroll
      for (int g = 0; g < 4; ++g) {
        bufA[g] = ((const float4*)xn)[g];
        bufB[g] = ((const float4*)en)[g];
      }
    }

    // ---- fragments: A[m=lane&15][k=quad*8+j], B[n=lane&15][k=quad*8+j] ----
    short8 a_hi[4], a_lo[4], b_hi[4], b_lo[4];
#pragma unroll
    for (int mi = 0; mi < 4; ++mi) {
      int row = wm + mi*16 + lcol;
      a_hi[mi] = *(const short8*)&Ahi[row*LDK + quad*8];
      a_lo[mi] = *(const short8*)&Alo[row*LDK + quad*8];
    }
#pragma unroll
    for (int ni = 0; ni < 4; ++ni) {
      int row = wn + ni*16 + lcol;
      b_hi[ni] = *(const short8*)&Bhi[row*LDK + quad*8];
      b_lo[ni] = *(const short8*)&Blo[row*LDK + quad*8];
    }
#pragma unroll
    for (int mi = 0; mi < 4; ++mi)
#pragma unroll
      for (int ni = 0; ni < 4; ++ni) {
        acc[mi][ni] = __builtin_amdgcn_mfma_f32_16x16x32_bf16(a_hi[mi], b_hi[ni], acc[mi][ni], 0, 0, 0);
        acc[mi][ni] = __builtin_amdgcn_mfma_f32_16x16x32_bf16(a_hi[mi], b_lo[ni], acc[mi][ni], 0, 0, 0);
        acc[mi][ni] = __builtin_amdgcn_mfma_f32_16x16x32_bf16(a_lo[mi], b_hi[ni], acc[mi][ni], 0, 0, 0);
      }
  }

  // ---- ||e||^2 chunk reduction: thread t holds partial for code (t>>1) ----
  esq_part[t] = esq_acc;
  __syncthreads();
  if (t < 128) esq_sh[t] = esq_part[2*t] + esq_part[2*t+1];
  __syncthreads();

  // ---- epilogue: C/D layout col=lane&15, row=quad*4+reg ----
#pragma unroll
  for (int mi = 0; mi < 4; ++mi)
#pragma unroll
    for (int ni = 0; ni < 4; ++ni)
#pragma unroll
      for (int reg = 0; reg < 4; ++reg) {
        int row = m0 + wm + mi*16 + quad*4 + reg;
        int cl  = wn + ni*16 + lcol;
        float val = esq_sh[cl] - 2.0f * acc[mi][ni][reg];
        atomicAdd(&scores[(size_t)row * Ndim + n0 + cl], val);
      }
}

// per-row top-2 (value,index) over 4096 approx scores
__global__ __launch_bounds__(256) void k_top2(const float* __restrict__ scores,
                                              int* __restrict__ top2) {
  __shared__ float sv1[256], sv2[256];
  __shared__ int   si1[256], si2[256];
  const int b = blockIdx.x, t = threadIdx.x;
  float v1 = 3.4e38f, v2 = 3.4e38f; int i1 = 0, i2 = 1;
  const float* row = scores + (size_t)b * Ndim;
#pragma unroll 4
  for (int i = 0; i < Ndim / 256; ++i) {
    int idx = t + i * 256;
    float v = row[idx];
    if (v < v1)      { v2 = v1; i2 = i1; v1 = v; i1 = idx; }
    else if (v < v2) { v2 = v;  i2 = idx; }
  }
  sv1[t] = v1; si1[t] = i1; sv2[t] = v2; si2[t] = i2;
  __syncthreads();
  for (int s = 128; s > 0; s >>= 1) {
    if (t < s) {
      float bv1 = sv1[t+s], bv2 = sv2[t+s];
      int   bi1 = si1[t+s], bi2 = si2[t+s];
      float av1 = sv1[t],   av2 = sv2[t];
      int   ai1 = si1[t],   ai2 = si2[t];
      if (bv1 < av1)      { av2 = av1; ai2 = ai1; av1 = bv1; ai1 = bi1; }
      else if (bv1 < av2) { av2 = bv1; ai2 = bi1; }
      if (bv2 < av2)      { av2 = bv2; ai2 = bi2; }
      sv1[t] = av1; si1[t] = ai1; sv2[t] = av2; si2[t] = ai2;
    }
    __syncthreads();
  }
  if (t == 0) { top2[2*b] = si1[0]; top2[2*b+1] = si2[0]; }
}

// exact fp32 re-score of the two candidates, then one-hot write (zeroes poison)
__global__ __launch_bounds__(256) void k_refine(const float* __restrict__ x,
                                                const float* __restrict__ e,
                                                const int* __restrict__ top2,
                                                float* __restrict__ out) {
  __shared__ float s1[256], s2[256];
  __shared__ int win_sh;
  const int b = blockIdx.x, t = threadIdx.x;
  const int i1 = top2[2*b], i2 = top2[2*b+1];
  const float4* xb = (const float4*)(x + (size_t)b  * Kdim);
  const float4* e1 = (const float4*)(e + (size_t)i1 * Kdim);
  const float4* e2 = (const float4*)(e + (size_t)i2 * Kdim);
  float a1 = 0.f, a2 = 0.f;
  for (int i = 0; i < Kdim / 4 / 256; ++i) {  // 16 iters of float4
    int q = t + i * 256;
    float4 xv  = xb[q];
    float4 ev1 = e1[q];
    float4 ev2 = e2[q];
    a1 += ev1.x*(ev1.x - 2.f*xv.x) + ev1.y*(ev1.y - 2.f*xv.y)
        + ev1.z*(ev1.z - 2.f*xv.z) + ev1.w*(ev1.w - 2.f*xv.w);
    a2 += ev2.x*(ev2.x - 2.f*xv.x) + ev2.y*(ev2.y - 2.f*xv.y)
        + ev2.z*(ev2.z - 2.f*xv.z) + ev2.w*(ev2.w - 2.f*xv.w);
  }
  s1[t] = a1; s2[t] = a2;
  __syncthreads();
  for (int s = 128; s > 0; s >>= 1) {
    if (t < s) { s1[t] += s1[t+s]; s2[t] += s2[t+s]; }
    __syncthreads();
  }
  if (t == 0) {
    float d1 = s1[0], d2 = s2[0];
    // np.argmin tie-break: smaller index wins on exact tie
    win_sh = (d2 < d1 || (d2 == d1 && i2 < i1)) ? i2 : i1;
  }
  __syncthreads();
  const int win = win_sh;
  float* outb = out + (size_t)b * Ndim;
#pragma unroll
  for (int g = 0; g < 4; ++g) {
    int q = g * 256 + t;  // float4 index, coalesced
    float4 v;
    v.x = (win == 4*q+0) ? 1.f : 0.f;
    v.y = (win == 4*q+1) ? 1.f : 0.f;
    v.z = (win == 4*q+2) ? 1.f : 0.f;
    v.w = (win == 4*q+3) ? 1.f : 0.f;
    ((float4*)outb)[q] = v;
  }
}

extern "C" void kernel_launch(void* const* d_in, const int* in_sizes, int n_in,
                              void* d_out, int out_size, void* d_ws, size_t ws_size,
                              hipStream_t stream) {
  (void)in_sizes; (void)n_in; (void)out_size; (void)ws_size;
  const float* x = (const float*)d_in[0];  // [256, 16384] fp32
  const float* e = (const float*)d_in[1];  // [4096, 16384] fp32
  float* scores  = (float*)d_out;          // reuse d_out as the [256,4096] score buffer
  int*   top2    = (int*)d_ws;             // 256 * 2 ints

  hipMemsetAsync(d_out, 0, (size_t)Mdim * Ndim * sizeof(float), stream);
  dim3 gG(Ndim / NT, Mdim / MT, KS);
  hipLaunchKernelGGL(k_gemm, gG, dim3(256), 0, stream, x, e, scores);
  hipLaunchKernelGGL(k_top2, dim3(Mdim), dim3(256), 0, stream, scores, top2);
  hipLaunchKernelGGL(k_refine, dim3(Mdim), dim3(256), 0, stream, x, e, top2, (float*)d_out);
}